// Round 6
// baseline (740.502 us; speedup 1.0000x reference)
//
#include <hip/hip_runtime.h>

namespace {

typedef float v2f __attribute__((ext_vector_type(2)));
typedef float v4f __attribute__((ext_vector_type(4)));

constexpr int kB = 4, kCin = 4, kCout = 4;
constexpr int kD1 = 32, kD2 = 32, kH = 64, kW = 64;
constexpr int kHO = 32, kWO = 32;
constexpr int kSlice = kH * kW;                       // 4096
constexpr size_t kCiStride = (size_t)kD1 * kD2 * kSlice;

__global__ __launch_bounds__(256, 3)
void conv4d_strang(const float* __restrict__ x, const float* __restrict__ w,
                   const float* __restrict__ bias, float* __restrict__ y,
                   const float* __restrict__ zbuf)
{
    // XCD-chunked decode: chunk=(b, h-half) -> each XCD owns a private 32MB
    // of x (H is not convolved). v-tile fastest for L2 halo locality.
    const unsigned orig  = blockIdx.x;       // 0..2047
    const unsigned chunk = orig & 7;
    const unsigned rem   = orig >> 3;        // 0..255
    const int b  = chunk >> 1;
    const int ht = chunk & 1;
    const int tu = rem >> 4;                 // 0..15
    const int tv = rem & 15;                 // 0..15
    const int u0 = 2 * tu, v0 = 2 * tv;

    const int wq = threadIdx.x;              // 0..15 -> outputs wo=2wq, 2wq+1
    const int hy = threadIdx.y;              // 0..15
    const int ho = ht * 16 + hy;             // 0..31
    const int toff = (2 * ho) * kW + 4 * wq;

    // acc[uu][vv][co][wo-sub], lanes = (kw-even, kw-odd) partials.
    v2f acc[2][2][kCout][2];
    #pragma unroll
    for (int co = 0; co < kCout; ++co) {
        const float bb = bias[co];
        #pragma unroll
        for (int uu = 0; uu < 2; ++uu)
            #pragma unroll
            for (int vv = 0; vv < 2; ++vv) {
                acc[uu][vv][co][0] = (v2f){bb, 0.f};
                acc[uu][vv][co][1] = (v2f){bb, 0.f};
            }
    }

    const float* xb = x + (size_t)b * kCin * kCiStride + toff;
    const float* zb = zbuf + toff;           // 16KB zeroed pad region

    #pragma unroll
    for (int e1 = 0; e1 < 4; ++e1) {
        const int d1 = u0 + e1 - 1;
        const bool ok1 = (unsigned)d1 < (unsigned)kD1;
        #pragma unroll
        for (int e2 = 0; e2 < 4; ++e2) {
            const int d2 = v0 + e2 - 1;
            const bool ok = ok1 && ((unsigned)d2 < (unsigned)kD2);
            // Uniform (SGPR) slice pointer: pad slices read zeros, ci-stride 0.
            const float* sp0 = ok ? (xb + (size_t)(d1 * kD2 + d2) * kSlice) : zb;
            const size_t cist = ok ? kCiStride : 0;

            // Batch all 8 independent 16B loads before any use (MLP=8).
            v4f r0[kCin], r1[kCin];
            #pragma unroll
            for (int ci = 0; ci < kCin; ++ci) {
                const float* sp = sp0 + (size_t)ci * cist;
                r0[ci] = *reinterpret_cast<const v4f*>(sp);
                r1[ci] = *reinterpret_cast<const v4f*>(sp + kW);
            }

            #pragma unroll
            for (int ci = 0; ci < kCin; ++ci) {
                #pragma unroll
                for (int uu = 0; uu < 2; ++uu) {
                    const int ku = e1 - uu;
                    if (ku < 0 || ku > 2) continue;      // compile-time
                    #pragma unroll
                    for (int vv = 0; vv < 2; ++vv) {
                        const int kv = e2 - vv;
                        if (kv < 0 || kv > 2) continue;  // compile-time
                        #pragma unroll
                        for (int co = 0; co < kCout; ++co) {
                            const float* wp = w + (((co * kCin + ci) * 3 + ku) * 3 + kv) * 4;
                            const v2f w01 = {wp[0], wp[1]};   // kh=0
                            const v2f w23 = {wp[2], wp[3]};   // kh=1
                            acc[uu][vv][co][0] = __builtin_elementwise_fma(
                                (v2f){r0[ci].x, r0[ci].y}, w01, acc[uu][vv][co][0]);
                            acc[uu][vv][co][0] = __builtin_elementwise_fma(
                                (v2f){r1[ci].x, r1[ci].y}, w23, acc[uu][vv][co][0]);
                            acc[uu][vv][co][1] = __builtin_elementwise_fma(
                                (v2f){r0[ci].z, r0[ci].w}, w01, acc[uu][vv][co][1]);
                            acc[uu][vv][co][1] = __builtin_elementwise_fma(
                                (v2f){r1[ci].z, r1[ci].w}, w23, acc[uu][vv][co][1]);
                        }
                    }
                }
            }
        }
    }

    #pragma unroll
    for (int co = 0; co < kCout; ++co)
        #pragma unroll
        for (int uu = 0; uu < 2; ++uu)
            #pragma unroll
            for (int vv = 0; vv < 2; ++vv) {
                v2f o;
                o.x = acc[uu][vv][co][0].x + acc[uu][vv][co][0].y;
                o.y = acc[uu][vv][co][1].x + acc[uu][vv][co][1].y;
                float* yp = y
                    + ((((size_t)(b * kCout + co) * kD1 + (u0 + uu)) * kD2 + (v0 + vv)) * kHO + ho) * kWO
                    + 2 * wq;
                *reinterpret_cast<v2f*>(yp) = o;
            }
}

}  // namespace

extern "C" void kernel_launch(void* const* d_in, const int* in_sizes, int n_in,
                              void* d_out, int out_size, void* d_ws, size_t ws_size,
                              hipStream_t stream) {
    const float* x    = (const float*)d_in[0];
    const float* w    = (const float*)d_in[1];
    const float* bias = (const float*)d_in[2];
    float* y          = (float*)d_out;

    // 16KB zero pad region in workspace (re-zeroed every call; deterministic,
    // graph-capturable).
    hipMemsetAsync(d_ws, 0, 16384, stream);

    dim3 block(16, 16, 1);
    dim3 grid(kB * 2 * 16 * 16, 1, 1);     // 2048 blocks
    hipLaunchKernelGGL(conv4d_strang, grid, block, 0, stream,
                       x, w, bias, y, (const float*)d_ws);
}

// Round 7
// 167.950 us; speedup vs baseline: 4.4091x; 4.4091x over previous
//
#include <hip/hip_runtime.h>

namespace {

typedef float v2f __attribute__((ext_vector_type(2)));
typedef float v4f __attribute__((ext_vector_type(4)));

constexpr int kB = 4, kCin = 4, kCout = 4;
constexpr int kD1 = 32, kD2 = 32, kH = 64, kW = 64;
constexpr int kHO = 32, kWO = 32;
constexpr int kSlice = kH * kW;                       // 4096
constexpr size_t kCiStride = (size_t)kD1 * kD2 * kSlice;

// One (d1,d2) slice's contribution: 8 x 16B loads + FMA nest.
// E1,E2 are compile-time after unrolling -> ku/kv guards fold away.
#define DO_SLICE(E1, E2, SP)                                                   \
  {                                                                            \
    v4f r0_[4], r1_[4];                                                        \
    _Pragma("unroll")                                                          \
    for (int ci = 0; ci < kCin; ++ci) {                                        \
      const float* sp_ = (SP) + (size_t)ci * kCiStride;                        \
      r0_[ci] = *reinterpret_cast<const v4f*>(sp_);                            \
      r1_[ci] = *reinterpret_cast<const v4f*>(sp_ + kW);                       \
    }                                                                          \
    _Pragma("unroll")                                                          \
    for (int ci = 0; ci < kCin; ++ci) {                                        \
      const v2f xa0 = r0_[ci].xy, xa1 = r0_[ci].zw;                            \
      const v2f xb0 = r1_[ci].xy, xb1 = r1_[ci].zw;                            \
      _Pragma("unroll")                                                        \
      for (int uu = 0; uu < 2; ++uu) {                                         \
        const int ku_ = (E1) - uu;                                             \
        if (ku_ < 0 || ku_ > 2) continue;                                      \
        _Pragma("unroll")                                                      \
        for (int vv = 0; vv < 2; ++vv) {                                       \
          const int kv_ = (E2) - vv;                                           \
          if (kv_ < 0 || kv_ > 2) continue;                                    \
          _Pragma("unroll")                                                    \
          for (int co = 0; co < kCout; ++co) {                                 \
            const float* wp_ =                                                 \
                w + (((co * kCin + ci) * 3 + ku_) * 3 + kv_) * 4;              \
            const v2f w01_ = {wp_[0], wp_[1]};                                 \
            const v2f w23_ = {wp_[2], wp_[3]};                                 \
            acc[uu][vv][co][0] =                                               \
                __builtin_elementwise_fma(xa0, w01_, acc[uu][vv][co][0]);      \
            acc[uu][vv][co][0] =                                               \
                __builtin_elementwise_fma(xb0, w23_, acc[uu][vv][co][0]);      \
            acc[uu][vv][co][1] =                                               \
                __builtin_elementwise_fma(xa1, w01_, acc[uu][vv][co][1]);      \
            acc[uu][vv][co][1] =                                               \
                __builtin_elementwise_fma(xb1, w23_, acc[uu][vv][co][1]);      \
          }                                                                    \
        }                                                                      \
      }                                                                        \
    }                                                                          \
  }

__global__ __launch_bounds__(256, 4)
void conv4d_strang(const float* __restrict__ x, const float* __restrict__ w,
                   const float* __restrict__ bias, float* __restrict__ y)
{
    // XCD-chunked decode: chunk=(b, h-half) -> each XCD owns a private 32MB
    // of x (H is not convolved). v-tile fastest for L2 halo locality.
    const unsigned orig  = blockIdx.x;       // 0..2047
    const unsigned chunk = orig & 7;         // XCD id under round-robin
    const unsigned rem   = orig >> 3;        // 0..255
    const int b  = chunk >> 1;
    const int ht = chunk & 1;
    const int tu = rem >> 4;                 // 0..15
    const int tv = rem & 15;                 // 0..15
    const int u0 = 2 * tu, v0 = 2 * tv;      // 2x2 (u,v) register tile

    const int wq = threadIdx.x;              // 0..15 -> outputs 2wq, 2wq+1
    const int hy = threadIdx.y;              // 0..15
    const int ho = ht * 16 + hy;             // 0..31
    const int toff = (2 * ho) * kW + 4 * wq;

    // acc[uu][vv][co][wo-sub], v2f lanes = (kw-even, kw-odd) partials.
    v2f acc[2][2][kCout][2];
    #pragma unroll
    for (int co = 0; co < kCout; ++co) {
        const float bb = bias[co];
        #pragma unroll
        for (int uu = 0; uu < 2; ++uu)
            #pragma unroll
            for (int vv = 0; vv < 2; ++vv) {
                acc[uu][vv][co][0] = (v2f){bb, 0.f};
                acc[uu][vv][co][1] = (v2f){bb, 0.f};
            }
    }

    const float* xb = x + (size_t)b * kCin * kCiStride + toff;

    if (tu >= 1 && tu <= 14 && tv >= 1 && tv <= 14) {
        // ---- Interior (77% of blocks): all 16 slices valid. One basic
        // block, 128 independent loads at compile-time offsets from a single
        // uniform base -> scheduler can hoist batches for latency hiding.
        const float* sb = xb + (size_t)((u0 - 1) * kD2 + (v0 - 1)) * kSlice;
        #pragma unroll
        for (int e1 = 0; e1 < 4; ++e1)
            #pragma unroll
            for (int e2 = 0; e2 < 4; ++e2) {
                const float* sp0 = sb + (size_t)(e1 * kD2 + e2) * kSlice;
                DO_SLICE(e1, e2, sp0);
            }
    } else {
        // ---- Boundary: wave-uniform skip of out-of-range slices.
        #pragma unroll
        for (int e1 = 0; e1 < 4; ++e1) {
            const int d1 = u0 + e1 - 1;
            if ((unsigned)d1 >= (unsigned)kD1) continue;
            #pragma unroll
            for (int e2 = 0; e2 < 4; ++e2) {
                const int d2 = v0 + e2 - 1;
                if ((unsigned)d2 >= (unsigned)kD2) continue;
                const float* sp0 = xb + (size_t)(d1 * kD2 + d2) * kSlice;
                DO_SLICE(e1, e2, sp0);
            }
        }
    }

    #pragma unroll
    for (int co = 0; co < kCout; ++co)
        #pragma unroll
        for (int uu = 0; uu < 2; ++uu)
            #pragma unroll
            for (int vv = 0; vv < 2; ++vv) {
                v2f o;
                o.x = acc[uu][vv][co][0].x + acc[uu][vv][co][0].y;
                o.y = acc[uu][vv][co][1].x + acc[uu][vv][co][1].y;
                float* yp = y
                    + ((((size_t)(b * kCout + co) * kD1 + (u0 + uu)) * kD2 + (v0 + vv)) * kHO + ho) * kWO
                    + 2 * wq;
                *reinterpret_cast<v2f*>(yp) = o;
            }
}

}  // namespace

extern "C" void kernel_launch(void* const* d_in, const int* in_sizes, int n_in,
                              void* d_out, int out_size, void* d_ws, size_t ws_size,
                              hipStream_t stream) {
    const float* x    = (const float*)d_in[0];
    const float* w    = (const float*)d_in[1];
    const float* bias = (const float*)d_in[2];
    float* y          = (float*)d_out;

    dim3 block(16, 16, 1);
    dim3 grid(kB * 2 * 16 * 16, 1, 1);     // 2048 blocks, decoded in-kernel
    hipLaunchKernelGGL(conv4d_strang, grid, block, 0, stream, x, w, bias, y);
}